// Round 2
// baseline (1076.140 us; speedup 1.0000x reference)
//
#include <hip/hip_runtime.h>

typedef __attribute__((ext_vector_type(8))) short s16x8;
typedef __attribute__((ext_vector_type(8))) unsigned short u16x8;
typedef __attribute__((ext_vector_type(4))) float f32x4;

#define LN_EPS 1e-5f

__device__ __forceinline__ unsigned short f2bf(float f) {
  unsigned int u = __float_as_uint(f);
  u += 0x7fffu + ((u >> 16) & 1u);
  return (unsigned short)(u >> 16);
}

__device__ __forceinline__ float gelu_exact(float x) {
  return 0.5f * x * (1.0f + erff(x * 0.70710678118654752f));
}

__device__ __forceinline__ s16x8 pack8(float4 a, float4 b) {
  u16x8 v;
  v[0] = f2bf(a.x); v[1] = f2bf(a.y); v[2] = f2bf(a.z); v[3] = f2bf(a.w);
  v[4] = f2bf(b.x); v[5] = f2bf(b.y); v[6] = f2bf(b.z); v[7] = f2bf(b.w);
  s16x8 r;
  #pragma unroll
  for (int i = 0; i < 8; ++i) r[i] = (short)v[i];
  return r;
}

// ws layout (ushort elems):
//   [0, 65536)        Wt1[n=256][k=256]  (= W1^T, bf16)
//   [65536, 98304)    Wt2[n=128][k=256]  (= W2^T, bf16)
//   [98304, 114688)   Wtm[n=128][k=128]  (= Wm[0:128]^T, bf16)
//   ushort off 114688: 128 f32 = Wm[128, :] (importance row, kept f32)
__global__ void prep_weights(const float* __restrict__ W1, const float* __restrict__ W2,
                             const float* __restrict__ Wm, unsigned short* __restrict__ ws) {
  int i = blockIdx.x * 256 + threadIdx.x;
  if (i < 65536) {
    int n = i >> 8, k = i & 255;
    ws[i] = f2bf(W1[k * 256 + n]);
  } else if (i < 98304) {
    int j = i - 65536; int n = j >> 8, k = j & 255;
    ws[i] = f2bf(W2[k * 128 + n]);
  } else if (i < 114688) {
    int j = i - 98304; int n = j >> 7, k = j & 127;
    ws[i] = f2bf(Wm[k * 128 + n]);
  } else if (i < 114816) {
    int c = i - 114688;
    reinterpret_cast<float*>(ws + 114688)[c] = Wm[128 * 128 + c];
  }
}

// 4 waves/block, 16 rows/wave, all LDS tiles wave-private -> no barriers.
__global__ __launch_bounds__(256, 3) void fused_edge_group(
    const float* __restrict__ emb, const int* __restrict__ eg,
    const float* __restrict__ imp,
    const float* __restrict__ b1, const float* __restrict__ g1, const float* __restrict__ be1,
    const float* __restrict__ b2, const float* __restrict__ g2, const float* __restrict__ be2,
    const float* __restrict__ bm,
    const unsigned short* __restrict__ ws,
    float* __restrict__ out, int G) {

  // per-wave: H1 16x256 bf16 (8KB, XOR-swizzled), H2 16x128 bf16 (4KB)
  __shared__ __align__(16) unsigned short lds_H1[4][16 * 256];
  __shared__ __align__(16) unsigned short lds_H2[4][16 * 128];

  const int tid = threadIdx.x;
  const int lane = tid & 63;
  const int wave = tid >> 6;
  const int l15 = lane & 15;
  const int lgrp = lane >> 4;   // 0..3
  const int g0 = blockIdx.x * 64;
  const int arow = wave * 16 + l15;   // block-local A row
  const int aswz = (l15 & 7) << 4;

  unsigned short* H1 = lds_H1[wave];
  unsigned short* H2 = lds_H2[wave];

  const unsigned short* wt1 = ws;
  const unsigned short* wt2 = ws + 65536;
  const unsigned short* wtm = ws + 98304;
  const float* wml = reinterpret_cast<const float*>(ws + 114688);

  // ---- gather A-fragments straight to registers ----
  // lane holds concat[row=arow][k = kk*32 + lgrp*8 .. +8]
  int grow = g0 + arow;
  int gc = grow < G ? grow : (G - 1);
  int2 e = *reinterpret_cast<const int2*>(eg + 2 * gc);
  s16x8 afrag[8];
  #pragma unroll
  for (int kk = 0; kk < 8; ++kk) {
    int idx = (kk < 4) ? e.x : e.y;
    const float4* p = reinterpret_cast<const float4*>(
        emb + (size_t)idx * 128 + (kk & 3) * 32 + lgrp * 8);
    afrag[kk] = pack8(p[0], p[1]);
  }

  // ---- GEMM1: [16 x 256] = A[16 x 256k] * Wt1 ----
  f32x4 acc1[16];
  #pragma unroll
  for (int nf = 0; nf < 16; ++nf) acc1[nf] = (f32x4){0.f, 0.f, 0.f, 0.f};
  for (int kk = 0; kk < 8; ++kk) {
    #pragma unroll
    for (int half = 0; half < 2; ++half) {
      s16x8 bfr[8];
      #pragma unroll
      for (int nf = 0; nf < 8; ++nf) {
        int n = (half * 8 + nf) * 16 + l15;
        bfr[nf] = *reinterpret_cast<const s16x8*>(wt1 + n * 256 + kk * 32 + lgrp * 8);
      }
      #pragma unroll
      for (int nf = 0; nf < 8; ++nf)
        acc1[half * 8 + nf] =
            __builtin_amdgcn_mfma_f32_16x16x32_bf16(afrag[kk], bfr[nf], acc1[half * 8 + nf], 0, 0, 0);
    }
  }

  // ---- epilogue 1: +b1, exact GELU, LayerNorm -> H1 (bf16, swizzled) ----
  {
    float s[4] = {0, 0, 0, 0}, q[4] = {0, 0, 0, 0};
    #pragma unroll
    for (int nf = 0; nf < 16; ++nf) {
      float bb = b1[nf * 16 + l15];
      #pragma unroll
      for (int r = 0; r < 4; ++r) {
        float x = acc1[nf][r] + bb;
        x = gelu_exact(x);
        acc1[nf][r] = x;
        s[r] += x; q[r] += x * x;
      }
    }
    #pragma unroll
    for (int m = 1; m < 16; m <<= 1) {
      #pragma unroll
      for (int r = 0; r < 4; ++r) { s[r] += __shfl_xor(s[r], m); q[r] += __shfl_xor(q[r], m); }
    }
    #pragma unroll
    for (int nf = 0; nf < 16; ++nf) {
      int col = nf * 16 + l15;
      float gam = g1[col], bet = be1[col];
      #pragma unroll
      for (int r = 0; r < 4; ++r) {
        float mu = s[r] * (1.f / 256.f);
        float var = q[r] * (1.f / 256.f) - mu * mu;
        float y = (acc1[nf][r] - mu) * rsqrtf(var + LN_EPS) * gam + bet;
        int row = lgrp * 4 + r;
        int byte = (row * 512 + col * 2) ^ ((row & 7) << 4);
        *reinterpret_cast<unsigned short*>(reinterpret_cast<char*>(H1) + byte) = f2bf(y);
      }
    }
  }
  asm volatile("s_waitcnt lgkmcnt(0)" ::: "memory");

  // ---- GEMM2: [16 x 128] = H1[16 x 256k] * Wt2 ----
  f32x4 acc2[8];
  #pragma unroll
  for (int nf = 0; nf < 8; ++nf) acc2[nf] = (f32x4){0.f, 0.f, 0.f, 0.f};
  for (int kk = 0; kk < 8; ++kk) {
    int abyte = (l15 * 512 + kk * 64 + lgrp * 16) ^ aswz;
    s16x8 af = *reinterpret_cast<const s16x8*>(reinterpret_cast<const char*>(H1) + abyte);
    s16x8 bfr[8];
    #pragma unroll
    for (int nf = 0; nf < 8; ++nf) {
      int n = nf * 16 + l15;
      bfr[nf] = *reinterpret_cast<const s16x8*>(wt2 + n * 256 + kk * 32 + lgrp * 8);
    }
    #pragma unroll
    for (int nf = 0; nf < 8; ++nf)
      acc2[nf] = __builtin_amdgcn_mfma_f32_16x16x32_bf16(af, bfr[nf], acc2[nf], 0, 0, 0);
  }

  // ---- epilogue 2: +b2, ReLU, LayerNorm -> H2 (bf16, swizzled) ----
  {
    float s[4] = {0, 0, 0, 0}, q[4] = {0, 0, 0, 0};
    #pragma unroll
    for (int nf = 0; nf < 8; ++nf) {
      float bb = b2[nf * 16 + l15];
      #pragma unroll
      for (int r = 0; r < 4; ++r) {
        float x = fmaxf(acc2[nf][r] + bb, 0.f);
        acc2[nf][r] = x;
        s[r] += x; q[r] += x * x;
      }
    }
    #pragma unroll
    for (int m = 1; m < 16; m <<= 1) {
      #pragma unroll
      for (int r = 0; r < 4; ++r) { s[r] += __shfl_xor(s[r], m); q[r] += __shfl_xor(q[r], m); }
    }
    #pragma unroll
    for (int nf = 0; nf < 8; ++nf) {
      int col = nf * 16 + l15;
      float gam = g2[col], bet = be2[col];
      #pragma unroll
      for (int r = 0; r < 4; ++r) {
        float mu = s[r] * (1.f / 128.f);
        float var = q[r] * (1.f / 128.f) - mu * mu;
        float y = (acc2[nf][r] - mu) * rsqrtf(var + LN_EPS) * gam + bet;
        int row = lgrp * 4 + r;
        int byte = (row * 256 + col * 2) ^ ((row & 7) << 4);
        *reinterpret_cast<unsigned short*>(reinterpret_cast<char*>(H2) + byte) = f2bf(y);
      }
    }
  }
  asm volatile("s_waitcnt lgkmcnt(0)" ::: "memory");

  // ---- GEMM3: [16 x 128] = H2[16 x 128k] * Wtm ----
  f32x4 acc3[8];
  #pragma unroll
  for (int nf = 0; nf < 8; ++nf) acc3[nf] = (f32x4){0.f, 0.f, 0.f, 0.f};
  for (int kk = 0; kk < 4; ++kk) {
    int abyte = (l15 * 256 + kk * 64 + lgrp * 16) ^ aswz;
    s16x8 af = *reinterpret_cast<const s16x8*>(reinterpret_cast<const char*>(H2) + abyte);
    s16x8 bfr[8];
    #pragma unroll
    for (int nf = 0; nf < 8; ++nf) {
      int n = nf * 16 + l15;
      bfr[nf] = *reinterpret_cast<const s16x8*>(wtm + n * 128 + kk * 32 + lgrp * 8);
    }
    #pragma unroll
    for (int nf = 0; nf < 8; ++nf)
      acc3[nf] = __builtin_amdgcn_mfma_f32_16x16x32_bf16(af, bfr[nf], acc3[nf], 0, 0, 0);
  }

  // ---- epilogue 3: + bm + imp * Wm[128,:], ReLU, store f32 ----
  {
    int growb = g0 + wave * 16 + lgrp * 4;
    float impv[4]; int gv[4];
    #pragma unroll
    for (int r = 0; r < 4; ++r) {
      int g = growb + r; gv[r] = g;
      impv[r] = imp[g < G ? g : (G - 1)];
    }
    #pragma unroll
    for (int nf = 0; nf < 8; ++nf) {
      int col = nf * 16 + l15;
      float bmv = bm[col], wlv = wml[col];
      #pragma unroll
      for (int r = 0; r < 4; ++r) {
        float y = acc3[nf][r] + bmv + impv[r] * wlv;
        y = fmaxf(y, 0.f);
        if (gv[r] < G) out[(size_t)gv[r] * 128 + col] = y;
      }
    }
  }
}

extern "C" void kernel_launch(void* const* d_in, const int* in_sizes, int n_in,
                              void* d_out, int out_size, void* d_ws, size_t ws_size,
                              hipStream_t stream) {
  const float* emb = (const float*)d_in[0];
  const int* eg    = (const int*)d_in[1];
  const float* imp = (const float*)d_in[2];
  const float* W1  = (const float*)d_in[3];
  const float* b1  = (const float*)d_in[4];
  const float* g1  = (const float*)d_in[5];
  const float* be1 = (const float*)d_in[6];
  const float* W2  = (const float*)d_in[7];
  const float* b2  = (const float*)d_in[8];
  const float* g2  = (const float*)d_in[9];
  const float* be2 = (const float*)d_in[10];
  const float* Wm  = (const float*)d_in[11];
  const float* bm  = (const float*)d_in[12];
  unsigned short* ws = (unsigned short*)d_ws;
  float* out = (float*)d_out;
  int G = in_sizes[2];

  prep_weights<<<(114816 + 255) / 256, 256, 0, stream>>>(W1, W2, Wm, ws);
  int nblk = (G + 63) / 64;
  fused_edge_group<<<nblk, 256, 0, stream>>>(emb, eg, imp, b1, g1, be1, b2, g2, be2, bm,
                                             ws, out, G);
}

// Round 3
// 921.598 us; speedup vs baseline: 1.1677x; 1.1677x over previous
//
#include <hip/hip_runtime.h>

typedef __attribute__((ext_vector_type(8))) short s16x8;
typedef __attribute__((ext_vector_type(8))) unsigned short u16x8;
typedef __attribute__((ext_vector_type(4))) float f32x4;

#define LN_EPS 1e-5f

__device__ __forceinline__ unsigned short f2bf(float f) {
  unsigned int u = __float_as_uint(f);
  u += 0x7fffu + ((u >> 16) & 1u);
  return (unsigned short)(u >> 16);
}

// tanh-approx GELU: max abs err vs exact ~1e-3, well inside threshold margin.
__device__ __forceinline__ float gelu_fast(float x) {
  float x2 = x * x;
  float y = x * (0.7978845608f + 0.03567740814f * x2);
  float ay = fabsf(y);
  float t = __expf(-2.0f * ay);            // v_mul + v_exp_f32
  float th = (1.0f - t) / (1.0f + t);      // sub, add, rcp, mul
  th = copysignf(th, y);
  return 0.5f * x * (1.0f + th);
}

__device__ __forceinline__ s16x8 pack8(float4 a, float4 b) {
  u16x8 v;
  v[0] = f2bf(a.x); v[1] = f2bf(a.y); v[2] = f2bf(a.z); v[3] = f2bf(a.w);
  v[4] = f2bf(b.x); v[5] = f2bf(b.y); v[6] = f2bf(b.z); v[7] = f2bf(b.w);
  s16x8 r;
  #pragma unroll
  for (int i = 0; i < 8; ++i) r[i] = (short)v[i];
  return r;
}

// ws layout (ushort elems) — FRAGMENT-MAJOR: B-fragment for (step,nf) stored as
// 64 lanes x 8 bf16 contiguous (1KB), so each wave load is one dense segment.
//   ws1 [0, 65536)      : GEMM1, step=kk*2+half (0..15), nf 0..7
//   ws2 [65536, 98304)  : GEMM2, kk 0..7, nf 0..7
//   ws3 [98304, 114688) : GEMM3, kk 0..3, nf 0..7
//   [114688, 114944)    : 128 f32 = Wm[128,:] (importance row)
__global__ void prep_weights(const float* __restrict__ W1, const float* __restrict__ W2,
                             const float* __restrict__ Wm, unsigned short* __restrict__ ws) {
  int i = blockIdx.x * 256 + threadIdx.x;
  if (i < 65536) {
    int f = i >> 9, lane = (i >> 3) & 63, j = i & 7;
    int step = f >> 3, nf = f & 7;
    int kk = step >> 1, half = step & 1;
    int n = (half * 8 + nf) * 16 + (lane & 15);
    int k = kk * 32 + (lane >> 4) * 8 + j;
    ws[i] = f2bf(W1[k * 256 + n]);
  } else if (i < 98304) {
    int t = i - 65536;
    int f = t >> 9, lane = (t >> 3) & 63, j = t & 7;
    int kk = f >> 3, nf = f & 7;
    int n = nf * 16 + (lane & 15);
    int k = kk * 32 + (lane >> 4) * 8 + j;
    ws[i] = f2bf(W2[k * 128 + n]);
  } else if (i < 114688) {
    int t = i - 98304;
    int f = t >> 9, lane = (t >> 3) & 63, j = t & 7;
    int kk = f >> 3, nf = f & 7;
    int n = nf * 16 + (lane & 15);
    int k = kk * 32 + (lane >> 4) * 8 + j;
    ws[i] = f2bf(Wm[k * 128 + n]);
  } else if (i < 114944) {
    int c = i - 114688;
    reinterpret_cast<float*>(ws + 114688)[c] = Wm[128 * 128 + c];
  }
}

// 4 waves/block, 16 rows/wave, wave-private LDS (8KB/wave, H2 aliases H1) -> no barriers.
__global__ __launch_bounds__(256, 5) void fused_edge_group(
    const float* __restrict__ emb, const int* __restrict__ eg,
    const float* __restrict__ imp,
    const float* __restrict__ b1, const float* __restrict__ g1, const float* __restrict__ be1,
    const float* __restrict__ b2, const float* __restrict__ g2, const float* __restrict__ be2,
    const float* __restrict__ bm,
    const unsigned short* __restrict__ ws,
    float* __restrict__ out, int G) {

  __shared__ __align__(16) unsigned short lds_H1[4][16 * 256];  // 8KB per wave

  const int tid = threadIdx.x;
  const int lane = tid & 63;
  const int wave = tid >> 6;
  const int l15 = lane & 15;
  const int lgrp = lane >> 4;   // 0..3
  const int g0 = blockIdx.x * 64;
  const int arow = wave * 16 + l15;
  const int aswz = (l15 & 7) << 4;

  unsigned short* H1 = lds_H1[wave];
  unsigned short* H2 = lds_H1[wave];   // aliased: H2 written after last H1 read

  const unsigned short* ws1 = ws;
  const unsigned short* ws2 = ws + 65536;
  const unsigned short* ws3 = ws + 98304;
  const float* wml = reinterpret_cast<const float*>(ws + 114688);

  // ---- gather A-fragments straight to registers ----
  int grow = g0 + arow;
  int gc = grow < G ? grow : (G - 1);
  int2 e = *reinterpret_cast<const int2*>(eg + 2 * gc);
  s16x8 afrag[8];
  #pragma unroll
  for (int kk = 0; kk < 8; ++kk) {
    int idx = (kk < 4) ? e.x : e.y;
    const float4* p = reinterpret_cast<const float4*>(
        emb + (size_t)idx * 128 + (kk & 3) * 32 + lgrp * 8);
    afrag[kk] = pack8(p[0], p[1]);
  }

  // ---- GEMM1: [16 x 256], B double-buffered, dense 1KB fragment loads ----
  f32x4 acc1[16];
  #pragma unroll
  for (int nf = 0; nf < 16; ++nf) acc1[nf] = (f32x4){0.f, 0.f, 0.f, 0.f};
  {
    s16x8 bA[8], bB[8];
    #pragma unroll
    for (int nf = 0; nf < 8; ++nf)
      bA[nf] = *reinterpret_cast<const s16x8*>(ws1 + nf * 512 + lane * 8);
    #pragma unroll
    for (int step = 0; step < 16; ++step) {
      const s16x8* cur = (step & 1) ? bB : bA;
      s16x8* nxt = (step & 1) ? bA : bB;
      if (step < 15) {
        #pragma unroll
        for (int nf = 0; nf < 8; ++nf)
          nxt[nf] = *reinterpret_cast<const s16x8*>(ws1 + ((step + 1) * 8 + nf) * 512 + lane * 8);
      }
      const int kk = step >> 1, half = step & 1;
      #pragma unroll
      for (int nf = 0; nf < 8; ++nf)
        acc1[half * 8 + nf] =
            __builtin_amdgcn_mfma_f32_16x16x32_bf16(afrag[kk], cur[nf], acc1[half * 8 + nf], 0, 0, 0);
    }
  }

  // ---- epilogue 1: +b1, fast GELU, LayerNorm -> H1 (bf16, swizzled) ----
  {
    float s[4] = {0, 0, 0, 0}, q[4] = {0, 0, 0, 0};
    #pragma unroll
    for (int nf = 0; nf < 16; ++nf) {
      float bb = b1[nf * 16 + l15];
      #pragma unroll
      for (int r = 0; r < 4; ++r) {
        float x = gelu_fast(acc1[nf][r] + bb);
        acc1[nf][r] = x;
        s[r] += x; q[r] += x * x;
      }
    }
    #pragma unroll
    for (int m = 1; m < 16; m <<= 1) {
      #pragma unroll
      for (int r = 0; r < 4; ++r) { s[r] += __shfl_xor(s[r], m); q[r] += __shfl_xor(q[r], m); }
    }
    float mu[4], rs[4];
    #pragma unroll
    for (int r = 0; r < 4; ++r) {
      mu[r] = s[r] * (1.f / 256.f);
      float var = q[r] * (1.f / 256.f) - mu[r] * mu[r];
      rs[r] = rsqrtf(var + LN_EPS);
    }
    #pragma unroll
    for (int nf = 0; nf < 16; ++nf) {
      int col = nf * 16 + l15;
      float gam = g1[col], bet = be1[col];
      #pragma unroll
      for (int r = 0; r < 4; ++r) {
        float y = (acc1[nf][r] - mu[r]) * rs[r] * gam + bet;
        int row = lgrp * 4 + r;
        int byte = (row * 512 + col * 2) ^ ((row & 7) << 4);
        *reinterpret_cast<unsigned short*>(reinterpret_cast<char*>(H1) + byte) = f2bf(y);
      }
    }
  }
  asm volatile("s_waitcnt lgkmcnt(0)" ::: "memory");

  // ---- GEMM2: [16 x 128] = H1[16 x 256k] * W2 ----
  f32x4 acc2[8];
  #pragma unroll
  for (int nf = 0; nf < 8; ++nf) acc2[nf] = (f32x4){0.f, 0.f, 0.f, 0.f};
  {
    s16x8 bA[8], bB[8];
    #pragma unroll
    for (int nf = 0; nf < 8; ++nf)
      bA[nf] = *reinterpret_cast<const s16x8*>(ws2 + nf * 512 + lane * 8);
    #pragma unroll
    for (int kk = 0; kk < 8; ++kk) {
      const s16x8* cur = (kk & 1) ? bB : bA;
      s16x8* nxt = (kk & 1) ? bA : bB;
      if (kk < 7) {
        #pragma unroll
        for (int nf = 0; nf < 8; ++nf)
          nxt[nf] = *reinterpret_cast<const s16x8*>(ws2 + ((kk + 1) * 8 + nf) * 512 + lane * 8);
      }
      int abyte = (l15 * 512 + kk * 64 + lgrp * 16) ^ aswz;
      s16x8 af = *reinterpret_cast<const s16x8*>(reinterpret_cast<const char*>(H1) + abyte);
      #pragma unroll
      for (int nf = 0; nf < 8; ++nf)
        acc2[nf] = __builtin_amdgcn_mfma_f32_16x16x32_bf16(af, cur[nf], acc2[nf], 0, 0, 0);
    }
  }

  // ---- epilogue 2: +b2, ReLU, LayerNorm -> H2 (bf16, swizzled; aliases H1) ----
  asm volatile("s_waitcnt lgkmcnt(0)" ::: "memory");  // drain H1 reads before overwrite
  {
    float s[4] = {0, 0, 0, 0}, q[4] = {0, 0, 0, 0};
    #pragma unroll
    for (int nf = 0; nf < 8; ++nf) {
      float bb = b2[nf * 16 + l15];
      #pragma unroll
      for (int r = 0; r < 4; ++r) {
        float x = fmaxf(acc2[nf][r] + bb, 0.f);
        acc2[nf][r] = x;
        s[r] += x; q[r] += x * x;
      }
    }
    #pragma unroll
    for (int m = 1; m < 16; m <<= 1) {
      #pragma unroll
      for (int r = 0; r < 4; ++r) { s[r] += __shfl_xor(s[r], m); q[r] += __shfl_xor(q[r], m); }
    }
    float mu[4], rs[4];
    #pragma unroll
    for (int r = 0; r < 4; ++r) {
      mu[r] = s[r] * (1.f / 128.f);
      float var = q[r] * (1.f / 128.f) - mu[r] * mu[r];
      rs[r] = rsqrtf(var + LN_EPS);
    }
    #pragma unroll
    for (int nf = 0; nf < 8; ++nf) {
      int col = nf * 16 + l15;
      float gam = g2[col], bet = be2[col];
      #pragma unroll
      for (int r = 0; r < 4; ++r) {
        float y = (acc2[nf][r] - mu[r]) * rs[r] * gam + bet;
        int row = lgrp * 4 + r;
        int byte = (row * 256 + col * 2) ^ ((row & 7) << 4);
        *reinterpret_cast<unsigned short*>(reinterpret_cast<char*>(H2) + byte) = f2bf(y);
      }
    }
  }
  asm volatile("s_waitcnt lgkmcnt(0)" ::: "memory");

  // ---- GEMM3: [16 x 128] = H2[16 x 128k] * Wm[0:128] ----
  f32x4 acc3[8];
  #pragma unroll
  for (int nf = 0; nf < 8; ++nf) acc3[nf] = (f32x4){0.f, 0.f, 0.f, 0.f};
  {
    s16x8 bA[8], bB[8];
    #pragma unroll
    for (int nf = 0; nf < 8; ++nf)
      bA[nf] = *reinterpret_cast<const s16x8*>(ws3 + nf * 512 + lane * 8);
    #pragma unroll
    for (int kk = 0; kk < 4; ++kk) {
      const s16x8* cur = (kk & 1) ? bB : bA;
      s16x8* nxt = (kk & 1) ? bA : bB;
      if (kk < 3) {
        #pragma unroll
        for (int nf = 0; nf < 8; ++nf)
          nxt[nf] = *reinterpret_cast<const s16x8*>(ws3 + ((kk + 1) * 8 + nf) * 512 + lane * 8);
      }
      int abyte = (l15 * 256 + kk * 64 + lgrp * 16) ^ aswz;
      s16x8 af = *reinterpret_cast<const s16x8*>(reinterpret_cast<const char*>(H2) + abyte);
      #pragma unroll
      for (int nf = 0; nf < 8; ++nf)
        acc3[nf] = __builtin_amdgcn_mfma_f32_16x16x32_bf16(af, cur[nf], acc3[nf], 0, 0, 0);
    }
  }

  // ---- epilogue 3: + bm + imp * Wm[128,:], ReLU, store f32 ----
  {
    int growb = g0 + wave * 16 + lgrp * 4;
    float impv[4]; int gv[4];
    #pragma unroll
    for (int r = 0; r < 4; ++r) {
      int g = growb + r; gv[r] = g;
      impv[r] = imp[g < G ? g : (G - 1)];
    }
    #pragma unroll
    for (int nf = 0; nf < 8; ++nf) {
      int col = nf * 16 + l15;
      float bmv = bm[col], wlv = wml[col];
      #pragma unroll
      for (int r = 0; r < 4; ++r) {
        float y = acc3[nf][r] + bmv + impv[r] * wlv;
        y = fmaxf(y, 0.f);
        if (gv[r] < G) out[(size_t)gv[r] * 128 + col] = y;
      }
    }
  }
}

extern "C" void kernel_launch(void* const* d_in, const int* in_sizes, int n_in,
                              void* d_out, int out_size, void* d_ws, size_t ws_size,
                              hipStream_t stream) {
  const float* emb = (const float*)d_in[0];
  const int* eg    = (const int*)d_in[1];
  const float* imp = (const float*)d_in[2];
  const float* W1  = (const float*)d_in[3];
  const float* b1  = (const float*)d_in[4];
  const float* g1  = (const float*)d_in[5];
  const float* be1 = (const float*)d_in[6];
  const float* W2  = (const float*)d_in[7];
  const float* b2  = (const float*)d_in[8];
  const float* g2  = (const float*)d_in[9];
  const float* be2 = (const float*)d_in[10];
  const float* Wm  = (const float*)d_in[11];
  const float* bm  = (const float*)d_in[12];
  unsigned short* ws = (unsigned short*)d_ws;
  float* out = (float*)d_out;
  int G = in_sizes[2];

  prep_weights<<<(114944 + 255) / 256, 256, 0, stream>>>(W1, W2, Wm, ws);
  int nblk = (G + 63) / 64;
  fused_edge_group<<<nblk, 256, 0, stream>>>(emb, eg, imp, b1, g1, be1, b2, g2, be2, bm,
                                             ws, out, G);
}

// Round 4
// 375.863 us; speedup vs baseline: 2.8631x; 2.4520x over previous
//
#include <hip/hip_runtime.h>

typedef __attribute__((ext_vector_type(8))) short s16x8;
typedef __attribute__((ext_vector_type(8))) unsigned short u16x8;
typedef __attribute__((ext_vector_type(4))) float f32x4;

#define LN_EPS 1e-5f

__device__ __forceinline__ unsigned short f2bf(float f) {
  unsigned int u = __float_as_uint(f);
  u += 0x7fffu + ((u >> 16) & 1u);
  return (unsigned short)(u >> 16);
}

__device__ __forceinline__ unsigned cvt_pk_bf16(float lo, float hi) {
  unsigned r;
  asm("v_cvt_pk_bf16_f32 %0, %1, %2" : "=v"(r) : "v"(lo), "v"(hi));
  return r;
}

// tanh-approx GELU: max abs err vs exact ~1e-3.
__device__ __forceinline__ float gelu_fast(float x) {
  float x2 = x * x;
  float y = x * (0.7978845608f + 0.03567740814f * x2);
  float ay = fabsf(y);
  float t = __expf(-2.0f * ay);
  float th = (1.0f - t) / (1.0f + t);
  th = copysignf(th, y);
  return 0.5f * x * (1.0f + th);
}

__device__ __forceinline__ s16x8 pack8(float4 a, float4 b) {
  u16x8 v;
  v[0] = f2bf(a.x); v[1] = f2bf(a.y); v[2] = f2bf(a.z); v[3] = f2bf(a.w);
  v[4] = f2bf(b.x); v[5] = f2bf(b.y); v[6] = f2bf(b.z); v[7] = f2bf(b.w);
  s16x8 r;
  #pragma unroll
  for (int i = 0; i < 8; ++i) r[i] = (short)v[i];
  return r;
}

// ws layout (ushort elems), all fragment-major (frag = 64 lanes x 8 bf16 = 1KB):
//   ws1 [0, 65536)      : GEMM1, frag idx f = ((g*8+kk)*4+nf), g 0..3, kk 0..7, nf 0..3
//   ws2 [65536, 98304)  : GEMM2, f = kk*8+nf, kk 0..7, nf 0..7
//   ws3 [98304, 114688) : GEMM3, f = kk*8+nf, kk 0..3, nf 0..7
//   [114688, 114944)    : 128 f32 = Wm[128,:] (importance row)
__global__ void prep_weights(const float* __restrict__ W1, const float* __restrict__ W2,
                             const float* __restrict__ Wm, unsigned short* __restrict__ ws) {
  int i = blockIdx.x * 256 + threadIdx.x;
  if (i < 65536) {
    int f = i >> 9, lane = (i >> 3) & 63, j = i & 7;
    int g = f >> 5, kk = (f >> 2) & 7, nf = f & 3;
    int n = g * 64 + nf * 16 + (lane & 15);
    int k = kk * 32 + (lane >> 4) * 8 + j;
    ws[i] = f2bf(W1[k * 256 + n]);
  } else if (i < 98304) {
    int t = i - 65536;
    int f = t >> 9, lane = (t >> 3) & 63, j = t & 7;
    int kk = f >> 3, nf = f & 7;
    int n = nf * 16 + (lane & 15);
    int k = kk * 32 + (lane >> 4) * 8 + j;
    ws[i] = f2bf(W2[k * 128 + n]);
  } else if (i < 114688) {
    int t = i - 98304;
    int f = t >> 9, lane = (t >> 3) & 63, j = t & 7;
    int kk = f >> 3, nf = f & 7;
    int n = nf * 16 + (lane & 15);
    int k = kk * 32 + (lane >> 4) * 8 + j;
    ws[i] = f2bf(Wm[k * 128 + n]);
  } else if (i < 114944) {
    int c = i - 114688;
    reinterpret_cast<float*>(ws + 114688)[c] = Wm[128 * 128 + c];
  }
}

// 4 waves/block, 16 rows/wave, wave-private LDS (8KB/wave, H2 aliases H1), no barriers.
// Register-budgeted for 128 VGPR (4 blocks/CU): GEMM1 processed in 4 N-groups.
__global__ __launch_bounds__(256, 4) void fused_edge_group(
    const float* __restrict__ emb, const int* __restrict__ eg,
    const float* __restrict__ imp,
    const float* __restrict__ b1, const float* __restrict__ g1, const float* __restrict__ be1,
    const float* __restrict__ b2, const float* __restrict__ g2, const float* __restrict__ be2,
    const float* __restrict__ bm,
    const unsigned short* __restrict__ ws,
    float* __restrict__ out, int G) {

  __shared__ __align__(16) unsigned short lds_H1[4][16 * 256];  // 8KB per wave

  const int tid = threadIdx.x;
  const int lane = tid & 63;
  const int wave = tid >> 6;
  const int l15 = lane & 15;
  const int lgrp = lane >> 4;   // 0..3
  const int g0 = blockIdx.x * 64;
  const int arow = wave * 16 + l15;
  const int aswz = (l15 & 7) << 4;

  unsigned short* H1 = lds_H1[wave];
  unsigned short* H2 = lds_H1[wave];   // aliased; wave-private, fenced

  const unsigned short* ws1 = ws;
  const unsigned short* ws2 = ws + 65536;
  const unsigned short* ws3 = ws + 98304;
  const float* wml = reinterpret_cast<const float*>(ws + 114688);

  // ---- gather A-fragments straight to registers ----
  int grow = g0 + arow;
  int gc = grow < G ? grow : (G - 1);
  int2 e = *reinterpret_cast<const int2*>(eg + 2 * gc);
  s16x8 afrag[8];
  #pragma unroll
  for (int kk = 0; kk < 8; ++kk) {
    int idx = (kk < 4) ? e.x : e.y;
    const float4* p = reinterpret_cast<const float4*>(
        emb + (size_t)idx * 128 + (kk & 3) * 32 + lgrp * 8);
    afrag[kk] = pack8(p[0], p[1]);
  }

  // ---- GEMM1: [16 x 256] in 4 N-groups of 64; only 16 acc regs live ----
  float s1[4] = {0, 0, 0, 0}, q1[4] = {0, 0, 0, 0};
  unsigned pk1[4][8];   // post-GELU, packed 2xbf16; fully unrolled -> regs
  #pragma unroll
  for (int g = 0; g < 4; ++g) {
    f32x4 acc[4];
    #pragma unroll
    for (int nf = 0; nf < 4; ++nf) acc[nf] = (f32x4){0.f, 0.f, 0.f, 0.f};
    s16x8 bA[4], bB[4];
    #pragma unroll
    for (int nf = 0; nf < 4; ++nf)
      bA[nf] = *reinterpret_cast<const s16x8*>(ws1 + ((g * 8 + 0) * 4 + nf) * 512 + lane * 8);
    #pragma unroll
    for (int kk = 0; kk < 8; ++kk) {
      const s16x8* cur = (kk & 1) ? bB : bA;
      s16x8* nxt = (kk & 1) ? bA : bB;
      if (kk < 7) {
        #pragma unroll
        for (int nf = 0; nf < 4; ++nf)
          nxt[nf] = *reinterpret_cast<const s16x8*>(ws1 + ((g * 8 + kk + 1) * 4 + nf) * 512 + lane * 8);
      }
      #pragma unroll
      for (int nf = 0; nf < 4; ++nf)
        acc[nf] = __builtin_amdgcn_mfma_f32_16x16x32_bf16(afrag[kk], cur[nf], acc[nf], 0, 0, 0);
    }
    // group epilogue: bias + GELU, accumulate LN stats in f32, pack to bf16
    #pragma unroll
    for (int nf = 0; nf < 4; ++nf) {
      float bb = b1[g * 64 + nf * 16 + l15];
      float x0 = gelu_fast(acc[nf][0] + bb);
      float x1 = gelu_fast(acc[nf][1] + bb);
      float x2 = gelu_fast(acc[nf][2] + bb);
      float x3 = gelu_fast(acc[nf][3] + bb);
      s1[0] += x0; q1[0] += x0 * x0;
      s1[1] += x1; q1[1] += x1 * x1;
      s1[2] += x2; q1[2] += x2 * x2;
      s1[3] += x3; q1[3] += x3 * x3;
      pk1[g][nf * 2 + 0] = cvt_pk_bf16(x0, x1);
      pk1[g][nf * 2 + 1] = cvt_pk_bf16(x2, x3);
    }
  }

  // ---- LN1: reduce stats, normalize packed values, write H1 (bf16, swizzled) ----
  {
    #pragma unroll
    for (int m = 1; m < 16; m <<= 1) {
      #pragma unroll
      for (int r = 0; r < 4; ++r) { s1[r] += __shfl_xor(s1[r], m); q1[r] += __shfl_xor(q1[r], m); }
    }
    float mu[4], rs[4];
    #pragma unroll
    for (int r = 0; r < 4; ++r) {
      mu[r] = s1[r] * (1.f / 256.f);
      float var = q1[r] * (1.f / 256.f) - mu[r] * mu[r];
      rs[r] = rsqrtf(var + LN_EPS);
    }
    #pragma unroll
    for (int g = 0; g < 4; ++g) {
      #pragma unroll
      for (int nf = 0; nf < 4; ++nf) {
        int col = g * 64 + nf * 16 + l15;
        float gam = g1[col], bet = be1[col];
        #pragma unroll
        for (int t = 0; t < 2; ++t) {
          unsigned p = pk1[g][nf * 2 + t];
          float xa = __uint_as_float(p << 16);
          float xb = __uint_as_float(p & 0xffff0000u);
          int r0 = t * 2, r1 = t * 2 + 1;
          float ya = (xa - mu[r0]) * rs[r0] * gam + bet;
          float yb = (xb - mu[r1]) * rs[r1] * gam + bet;
          int rowa = lgrp * 4 + r0, rowb = lgrp * 4 + r1;
          int bytea = (rowa * 512 + col * 2) ^ ((rowa & 7) << 4);
          int byteb = (rowb * 512 + col * 2) ^ ((rowb & 7) << 4);
          *reinterpret_cast<unsigned short*>(reinterpret_cast<char*>(H1) + bytea) = f2bf(ya);
          *reinterpret_cast<unsigned short*>(reinterpret_cast<char*>(H1) + byteb) = f2bf(yb);
        }
      }
    }
  }
  asm volatile("s_waitcnt lgkmcnt(0)" ::: "memory");

  // ---- GEMM2: [16 x 128] = H1[16 x 256k] * W2 ----
  f32x4 acc2[8];
  #pragma unroll
  for (int nf = 0; nf < 8; ++nf) acc2[nf] = (f32x4){0.f, 0.f, 0.f, 0.f};
  {
    s16x8 bA[8], bB[8];
    #pragma unroll
    for (int nf = 0; nf < 8; ++nf)
      bA[nf] = *reinterpret_cast<const s16x8*>(ws2 + nf * 512 + lane * 8);
    #pragma unroll
    for (int kk = 0; kk < 8; ++kk) {
      const s16x8* cur = (kk & 1) ? bB : bA;
      s16x8* nxt = (kk & 1) ? bA : bB;
      if (kk < 7) {
        #pragma unroll
        for (int nf = 0; nf < 8; ++nf)
          nxt[nf] = *reinterpret_cast<const s16x8*>(ws2 + ((kk + 1) * 8 + nf) * 512 + lane * 8);
      }
      int abyte = (l15 * 512 + kk * 64 + lgrp * 16) ^ aswz;
      s16x8 af = *reinterpret_cast<const s16x8*>(reinterpret_cast<const char*>(H1) + abyte);
      #pragma unroll
      for (int nf = 0; nf < 8; ++nf)
        acc2[nf] = __builtin_amdgcn_mfma_f32_16x16x32_bf16(af, cur[nf], acc2[nf], 0, 0, 0);
    }
  }

  // ---- epilogue 2: +b2, ReLU, LayerNorm -> H2 (bf16, swizzled; aliases H1) ----
  asm volatile("s_waitcnt lgkmcnt(0)" ::: "memory");  // drain H1 reads before overwrite
  {
    float s[4] = {0, 0, 0, 0}, q[4] = {0, 0, 0, 0};
    #pragma unroll
    for (int nf = 0; nf < 8; ++nf) {
      float bb = b2[nf * 16 + l15];
      #pragma unroll
      for (int r = 0; r < 4; ++r) {
        float x = fmaxf(acc2[nf][r] + bb, 0.f);
        acc2[nf][r] = x;
        s[r] += x; q[r] += x * x;
      }
    }
    #pragma unroll
    for (int m = 1; m < 16; m <<= 1) {
      #pragma unroll
      for (int r = 0; r < 4; ++r) { s[r] += __shfl_xor(s[r], m); q[r] += __shfl_xor(q[r], m); }
    }
    float mu[4], rs[4];
    #pragma unroll
    for (int r = 0; r < 4; ++r) {
      mu[r] = s[r] * (1.f / 128.f);
      float var = q[r] * (1.f / 128.f) - mu[r] * mu[r];
      rs[r] = rsqrtf(var + LN_EPS);
    }
    #pragma unroll
    for (int nf = 0; nf < 8; ++nf) {
      int col = nf * 16 + l15;
      float gam = g2[col], bet = be2[col];
      #pragma unroll
      for (int r = 0; r < 4; ++r) {
        float y = (acc2[nf][r] - mu[r]) * rs[r] * gam + bet;
        int row = lgrp * 4 + r;
        int byte = (row * 256 + col * 2) ^ ((row & 7) << 4);
        *reinterpret_cast<unsigned short*>(reinterpret_cast<char*>(H2) + byte) = f2bf(y);
      }
    }
  }
  asm volatile("s_waitcnt lgkmcnt(0)" ::: "memory");

  // ---- GEMM3: [16 x 128] = H2[16 x 128k] * Wm[0:128] ----
  f32x4 acc3[8];
  #pragma unroll
  for (int nf = 0; nf < 8; ++nf) acc3[nf] = (f32x4){0.f, 0.f, 0.f, 0.f};
  {
    s16x8 bA[8], bB[8];
    #pragma unroll
    for (int nf = 0; nf < 8; ++nf)
      bA[nf] = *reinterpret_cast<const s16x8*>(ws3 + nf * 512 + lane * 8);
    #pragma unroll
    for (int kk = 0; kk < 4; ++kk) {
      const s16x8* cur = (kk & 1) ? bB : bA;
      s16x8* nxt = (kk & 1) ? bA : bB;
      if (kk < 3) {
        #pragma unroll
        for (int nf = 0; nf < 8; ++nf)
          nxt[nf] = *reinterpret_cast<const s16x8*>(ws3 + ((kk + 1) * 8 + nf) * 512 + lane * 8);
      }
      int abyte = (l15 * 256 + kk * 64 + lgrp * 16) ^ aswz;
      s16x8 af = *reinterpret_cast<const s16x8*>(reinterpret_cast<const char*>(H2) + abyte);
      #pragma unroll
      for (int nf = 0; nf < 8; ++nf)
        acc3[nf] = __builtin_amdgcn_mfma_f32_16x16x32_bf16(af, cur[nf], acc3[nf], 0, 0, 0);
    }
  }

  // ---- epilogue 3: + bm + imp * Wm[128,:], ReLU, store f32 ----
  {
    int growb = g0 + wave * 16 + lgrp * 4;
    float impv[4]; int gv[4];
    #pragma unroll
    for (int r = 0; r < 4; ++r) {
      int g = growb + r; gv[r] = g;
      impv[r] = imp[g < G ? g : (G - 1)];
    }
    #pragma unroll
    for (int nf = 0; nf < 8; ++nf) {
      int col = nf * 16 + l15;
      float bmv = bm[col], wlv = wml[col];
      #pragma unroll
      for (int r = 0; r < 4; ++r) {
        float y = acc3[nf][r] + bmv + impv[r] * wlv;
        y = fmaxf(y, 0.f);
        if (gv[r] < G) out[(size_t)gv[r] * 128 + col] = y;
      }
    }
  }
}

extern "C" void kernel_launch(void* const* d_in, const int* in_sizes, int n_in,
                              void* d_out, int out_size, void* d_ws, size_t ws_size,
                              hipStream_t stream) {
  const float* emb = (const float*)d_in[0];
  const int* eg    = (const int*)d_in[1];
  const float* imp = (const float*)d_in[2];
  const float* W1  = (const float*)d_in[3];
  const float* b1  = (const float*)d_in[4];
  const float* g1  = (const float*)d_in[5];
  const float* be1 = (const float*)d_in[6];
  const float* W2  = (const float*)d_in[7];
  const float* b2  = (const float*)d_in[8];
  const float* g2  = (const float*)d_in[9];
  const float* be2 = (const float*)d_in[10];
  const float* Wm  = (const float*)d_in[11];
  const float* bm  = (const float*)d_in[12];
  unsigned short* ws = (unsigned short*)d_ws;
  float* out = (float*)d_out;
  int G = in_sizes[2];

  prep_weights<<<(114944 + 255) / 256, 256, 0, stream>>>(W1, W2, Wm, ws);
  int nblk = (G + 63) / 64;
  fused_edge_group<<<nblk, 256, 0, stream>>>(emb, eg, imp, b1, g1, be1, b2, g2, be2, bm,
                                             ws, out, G);
}